// Round 1
// baseline (530.242 us; speedup 1.0000x reference)
//
#include <hip/hip_runtime.h>
#include <stdint.h>

typedef __attribute__((ext_vector_type(8))) short short8;
typedef __attribute__((ext_vector_type(4))) float floatx4;

__device__ __forceinline__ unsigned short f2bf(float x) {
    unsigned int u = __builtin_bit_cast(unsigned int, x);
    unsigned int r = (u + 0x7FFFu + ((u >> 16) & 1u)) >> 16;   // RNE
    return (unsigned short)r;
}

// ---- W f32 -> bf16 (524288 elements, x4 vectorized) ----
__global__ void wconv(const float4* __restrict__ W4, ushort4* __restrict__ Wb4) {
    int i = blockIdx.x * 256 + threadIdx.x;   // 131072 threads
    float4 v = W4[i];
    ushort4 o;
    o.x = f2bf(v.x); o.y = f2bf(v.y); o.z = f2bf(v.z); o.w = f2bf(v.w);
    Wb4[i] = o;
}

// ---- level 0: h0 = bf16(tanh(emb[ids])), [131072][512] ----
__global__ void embed_tanh(const int* __restrict__ ids, const float* __restrict__ emb,
                           ushort* __restrict__ h0) {
    int idx = blockIdx.x * 256 + threadIdx.x;   // 16,777,216 threads
    int e = idx * 4;
    int row = e >> 9;
    int col = e & 511;
    int id = ids[row];
    const float4 v = *reinterpret_cast<const float4*>(emb + (size_t)id * 512 + col);
    ushort4 o;
    o.x = f2bf(tanhf(v.x)); o.y = f2bf(tanhf(v.y));
    o.z = f2bf(tanhf(v.z)); o.w = f2bf(tanhf(v.w));
    *reinterpret_cast<ushort4*>(h0 + e) = o;
}

// ---- one tree level: out[M][512] = tanh(A[M][1024] @ W^T + b) ----
// A = previous level's h viewed as [M][1024] (sibling concat is contiguous).
// 128x128 tile, BK=32, 4 waves (2x2), per-wave 64x64 = 4x4 16x16x32 MFMA frags.
__global__ __launch_bounds__(256)
void level_gemm(const ushort* __restrict__ A, const ushort* __restrict__ Bt,
                const float* __restrict__ bias,
                ushort* __restrict__ outb, float* __restrict__ outf,
                int M, int last)
{
    __shared__ alignas(16) ushort sA[128][32];
    __shared__ alignas(16) ushort sB[128][32];

    const int tid  = threadIdx.x;
    const int lane = tid & 63;
    const int w    = tid >> 6;
    const int wr   = w >> 1, wc = w & 1;
    const int m0   = blockIdx.x * 128;
    const int n0   = blockIdx.y * 128;

    floatx4 acc[4][4] = {};

    // staging coords: thread t -> row (t>>2) (+64 second pass), 8-elem k-chunk (t&3)*8
    const int sr = tid >> 2;
    const int sc = (tid & 3) * 8;
    const ushort* Ag = A  + (size_t)(m0 + sr) * 1024 + sc;
    const ushort* Bg = Bt + (size_t)(n0 + sr) * 1024 + sc;

    const int kk = (lane >> 4) * 8;
    const int rA = wr * 64 + (lane & 15);
    const int rB = wc * 64 + (lane & 15);

    for (int k0 = 0; k0 < 1024; k0 += 32) {
        __builtin_amdgcn_global_load_lds(
            (const __attribute__((address_space(1))) void*)(Ag + k0),
            (__attribute__((address_space(3))) void*)&sA[sr][sc], 16, 0, 0);
        __builtin_amdgcn_global_load_lds(
            (const __attribute__((address_space(1))) void*)(Ag + 64 * 1024 + k0),
            (__attribute__((address_space(3))) void*)&sA[64 + sr][sc], 16, 0, 0);
        __builtin_amdgcn_global_load_lds(
            (const __attribute__((address_space(1))) void*)(Bg + k0),
            (__attribute__((address_space(3))) void*)&sB[sr][sc], 16, 0, 0);
        __builtin_amdgcn_global_load_lds(
            (const __attribute__((address_space(1))) void*)(Bg + 64 * 1024 + k0),
            (__attribute__((address_space(3))) void*)&sB[64 + sr][sc], 16, 0, 0);
        __syncthreads();   // drains vmcnt before ds_read

        short8 a[4], bq[4];
        #pragma unroll
        for (int mi = 0; mi < 4; ++mi)
            a[mi] = *reinterpret_cast<const short8*>(&sA[rA + mi * 16][kk]);
        #pragma unroll
        for (int ni = 0; ni < 4; ++ni)
            bq[ni] = *reinterpret_cast<const short8*>(&sB[rB + ni * 16][kk]);
        #pragma unroll
        for (int mi = 0; mi < 4; ++mi)
            #pragma unroll
            for (int ni = 0; ni < 4; ++ni)
                acc[mi][ni] = __builtin_amdgcn_mfma_f32_16x16x32_bf16(
                    a[mi], bq[ni], acc[mi][ni], 0, 0, 0);
        __syncthreads();
    }

    // epilogue: D mapping col = lane&15, row = (lane>>4)*4 + j  (m89/m91 verified)
    const int mrow = (lane >> 4) * 4;
    const int ncol = lane & 15;
    #pragma unroll
    for (int mi = 0; mi < 4; ++mi) {
        #pragma unroll
        for (int ni = 0; ni < 4; ++ni) {
            const int n = n0 + wc * 64 + ni * 16 + ncol;
            const float bb = bias[n];
            #pragma unroll
            for (int j = 0; j < 4; ++j) {
                const int m = m0 + wr * 64 + mi * 16 + mrow + j;
                if (m < M) {
                    float v = tanhf(acc[mi][ni][j] + bb);
                    if (last) outf[(size_t)m * 512 + n] = v;
                    else      outb[(size_t)m * 512 + n] = f2bf(v);
                }
            }
        }
    }
}

extern "C" void kernel_launch(void* const* d_in, const int* in_sizes, int n_in,
                              void* d_out, int out_size, void* d_ws, size_t ws_size,
                              hipStream_t stream) {
    const int*   ids  = (const int*)d_in[0];
    const float* emb  = (const float*)d_in[1];
    const float* W    = (const float*)d_in[2];
    const float* bias = (const float*)d_in[3];
    float* out = (float*)d_out;

    // ws layout: Wb (1 MiB) | hA (128 MiB, 131072x512 bf16) | hB (64 MiB)
    unsigned short* Wb = (unsigned short*)d_ws;
    unsigned short* hA = Wb + 524288;
    unsigned short* hB = hA + 67108864;

    wconv<<<512, 256, 0, stream>>>((const float4*)W, (ushort4*)Wb);
    embed_tanh<<<65536, 256, 0, stream>>>(ids, emb, hA);

    int M = 65536;
    for (int l = 1; l <= 11; ++l) {
        const unsigned short* in = (l & 1) ? hA : hB;
        unsigned short*       ob = (l & 1) ? hB : hA;
        int gm = (M + 127) / 128;
        dim3 grid(gm, 4);
        level_gemm<<<grid, 256, 0, stream>>>(in, Wb, bias, ob, out, M, l == 11 ? 1 : 0);
        M >>= 1;
    }
}